// Round 1
// baseline (10.470 us; speedup 1.0000x reference)
//
#include <hip/hip_runtime.h>
#include <hip/hip_bf16.h>

// Problem constants (match the reference)
#define BB 128   // batch
#define LL 128   // seq len
// VOCAB_P1 = 1024 (unused: identity embedding collapses to token equality)

// out[b][q][c] = (qry[b][q] == cnd[b][c] && qry[b][q] > 0) ? 1.0f : 0.0f
// (equality with qry>0 implies cnd>0, so one validity check suffices)

#define QROWS 16                     // q-rows per block
#define BLOCKS_PER_B (LL / QROWS)    // 8
#define F4_PER_ROW (LL / 4)          // 32 float4 per c-row

__global__ __launch_bounds__(256)
void align_binary_kernel(const int* __restrict__ qry,
                         const int* __restrict__ cnd,
                         float4* __restrict__ out) {
    const int blk = blockIdx.x;
    const int b  = blk / BLOCKS_PER_B;
    const int q0 = (blk % BLOCKS_PER_B) * QROWS;
    const int t  = threadIdx.x;

    __shared__ int s_cnd[LL];
    __shared__ int s_qry[QROWS];
    if (t < LL)    s_cnd[t] = cnd[b * LL + t];
    if (t < QROWS) s_qry[t] = qry[b * LL + q0 + t];
    __syncthreads();

    // Block emits QROWS * LL = 2048 floats = 512 float4; 256 threads -> 2 each.
    const int4* s_cnd4 = reinterpret_cast<const int4*>(s_cnd);
#pragma unroll
    for (int it = 0; it < 2; ++it) {
        const int i  = it * 256 + t;   // 0..511
        const int q  = i >> 5;         // i / F4_PER_ROW
        const int c4 = i & 31;         // i % F4_PER_ROW

        const int  qv    = s_qry[q];
        const bool valid = (qv > 0);
        const int4 cv    = s_cnd4[c4];

        float4 r;
        r.x = (valid && cv.x == qv) ? 1.0f : 0.0f;
        r.y = (valid && cv.y == qv) ? 1.0f : 0.0f;
        r.z = (valid && cv.z == qv) ? 1.0f : 0.0f;
        r.w = (valid && cv.w == qv) ? 1.0f : 0.0f;

        out[((size_t)(b * LL + q0 + q)) * F4_PER_ROW + c4] = r;
    }
}

extern "C" void kernel_launch(void* const* d_in, const int* in_sizes, int n_in,
                              void* d_out, int out_size, void* d_ws, size_t ws_size,
                              hipStream_t stream) {
    // setup_inputs order: emb_weight (f32, unused), qry_lkup (i32), cnd_lkup (i32)
    const int* qry = (const int*)d_in[1];
    const int* cnd = (const int*)d_in[2];
    float4* out = (float4*)d_out;

    const int grid = BB * BLOCKS_PER_B;  // 1024 blocks
    align_binary_kernel<<<grid, 256, 0, stream>>>(qry, cnd, out);
}